// Round 5
// baseline (320.513 us; speedup 1.0000x reference)
//
#include <hip/hip_runtime.h>

// GCN link predictor. fp32 math, bf16 intermediates + bf16 MFMA GEMM.
// Pipeline: memset(cnts) -> stage1[node-direct scatter + pair scatter + Wprepack] ->
//           gemm1 -> agg1 -> gemm2 -> agg2 -> decode-bucket.   (7 dispatches)
// norm factorization: h'[i] = dinv[i]*(x@W)[i];  z[i] = dinv[i]*(h'[i] + sum_{src->i} h'[src]) + b.
// R5: MFMA GEMM. R6 FAILED: hot per-row global atomics. R7: deterministic bucket CSR. R8: 248us.
// R9 FAILED: grid.sync. R10: quarter-wave gathers (neutral; random-line floor ~4.5TB/s).
// R11 FAILED: agg1+gemm2 fusion. R12: fuse scatter+gemm1 (244.8us). R13 FAILED: column-pass
// L2 blocking (no XCD locality). R14 (~neutral): decode A-bucket (4B random touches refund).
// R15 (228.7us): reserve-based staging, pb embedded in pair rec. R16 (211.4us): stage1
// occupancy 4%->full (256x1024). R17: node-direct one-pass scatter -- srcs[n*64+pos] with
// pos=atomicAdd(&ncnt[n],1) (16 adds/counter, L2-resident). Deletes stageE (2 random passes
// -> 1), deletes scatter_gemm phase-1 entirely (pure gemm now), deletes rpd+dinv buffers
// (deg/dinv derived from ncnt). Pairs one-pass via pcnt[b] atomics (512/counter, ok).
// aggs remain at the random-gather floor (~45us each) -- structural for uniform random graph.

typedef __attribute__((ext_vector_type(8))) short short8;   // 8 bf16 (A/B frag)
typedef __attribute__((ext_vector_type(4))) float floatx4;  // C/D frag

#define STAGE_G 2048  // staging blocks
#define STAGE_T 256   // staging threads/block
#define NCAP 64       // per-node src capacity (deg~Poisson(16); P(deg>64)~1e-56, guarded)
#define PCAP 1024     // per-bucket pair capacity (lambda~511)

__device__ __forceinline__ unsigned short f2bf(float f) {
    union { float f; unsigned int u; } v; v.f = f;
    unsigned int u = v.u;
    u += 0x7fffu + ((u >> 16) & 1u);   // round-to-nearest-even
    return (unsigned short)(u >> 16);
}

__device__ __forceinline__ unsigned int pack2(float a, float b) {
    return (unsigned int)f2bf(a) | ((unsigned int)f2bf(b) << 16);
}

__device__ __forceinline__ float4 cvt4(unsigned int lo, unsigned int hi) {
    float4 f;
    f.x = __uint_as_float(lo << 16);
    f.y = __uint_as_float(lo & 0xffff0000u);
    f.z = __uint_as_float(hi << 16);
    f.w = __uint_as_float(hi & 0xffff0000u);
    return f;
}

// --- one-pass node-direct staging (edges) + bucket staging (pairs) + W prepack ---
// No LDS, no barriers: stream reads, one global atomic + one random store per record.
// 2048x256 = up to 32 waves/CU to hide the atomic->store latency chain.
__global__ __launch_bounds__(256) void stage1_kernel(const int* __restrict__ src,
                                                     const int* __restrict__ dst,
                                                     const int* __restrict__ pa,
                                                     const int* __restrict__ pb,
                                                     int* __restrict__ ncnt,
                                                     int* __restrict__ pcnt,
                                                     int* __restrict__ srcs,
                                                     uint2* __restrict__ stageP,
                                                     const float* __restrict__ W1,
                                                     const float* __restrict__ W2,
                                                     short* __restrict__ wb1,
                                                     short* __restrict__ wb2,
                                                     int E, int P) {
    int t = threadIdx.x, g = blockIdx.x;

    // one-time W prepack into MFMA B layout: WB[((nt*4+kt)*64+ln)*8+j]  (blocks 0..31)
    if (g < 32) {
        const float4* W4 = (const float4*)((g < 16) ? W1 : W2);
        short* wb = (g < 16) ? wb1 : wb2;
        int f = ((g & 15) * 256) + t;          // f in [0,4096)
        int k = f >> 5;
        int c4 = f & 31;
        float4 wv = W4[f];
        int kt = k >> 5, q = (k >> 3) & 3, j = k & 7;
        float e[4] = {wv.x, wv.y, wv.z, wv.w};
#pragma unroll
        for (int m = 0; m < 4; ++m) {
            int c = c4 * 4 + m;
            int nt = c >> 4;
            int ln = q * 16 + (c & 15);
            wb[((nt * 4 + kt) * 64 + ln) * 8 + j] = (short)f2bf(e[m]);
        }
    }

    int chunk = (E + gridDim.x - 1) / gridDim.x;
    int lo = g * chunk, hi = min(lo + chunk, E);
    for (int i = lo + t; i < hi; i += STAGE_T) {
        int n = dst[i];
        int pos = atomicAdd(&ncnt[n], 1);
        if (pos < NCAP) srcs[((size_t)n << 6) + pos] = src[i];
    }

    int chunkP = (P + gridDim.x - 1) / gridDim.x;
    int loP = g * chunkP, hiP = min(loP + chunkP, P);
    for (int i = loP + t; i < hiP; i += STAGE_T) {
        int A = pa[i];
        int b = A >> 6;
        int pos = atomicAdd(&pcnt[b], 1);
        if (pos < PCAP) {
            uint2 r;
            r.x = ((unsigned int)pb[i] << 6) | (unsigned int)(A & 63);  // B < 2^26
            r.y = (unsigned int)i;
            stageP[((size_t)b << 10) + pos] = r;
        }
    }
}

// --- layer-1 MFMA GEMM (fp32 input, prepacked W, dinv from ncnt) ---
__global__ __launch_bounds__(256) void gemm1_kernel(const float* __restrict__ Xv,
                                                    const short* __restrict__ wbpre,
                                                    const int* __restrict__ ncnt,
                                                    uint2* __restrict__ H, int N) {
    __shared__ __align__(16) char smem[50176];
    short* WB = (short*)smem;            // [nt][kt][lane][j]
    short* XL = (short*)(smem + 32768);  // [row][k], row stride 136 shorts
    float* Cst = (float*)smem;           // epilogue overlay: [row][col], stride 132 floats

    const int tid = threadIdx.x;
    const int w = tid >> 6;
    const int lane = tid & 63;
    const int blk = blockIdx.x;

    {
        const uint4* Wp = (const uint4*)wbpre;
        uint4* WB4 = (uint4*)WB;
#pragma unroll
        for (int i = 0; i < 8; ++i) {
            int idx = tid + i * 256;   // [0,2048)
            WB4[idx] = Wp[idx];
        }
    }
    {
#pragma unroll
        for (int i = 0; i < 8; ++i) {
            int f = tid + i * 256;
            int row = f >> 5;
            int c4 = f & 31;
            int gr = min(blk * 64 + row, N - 1);
            float4 xv = ((const float4*)Xv)[(size_t)gr * 32 + c4];
            uint2 u;
            u.x = pack2(xv.x, xv.y);
            u.y = pack2(xv.z, xv.w);
            *(uint2*)&XL[row * 136 + c4 * 4] = u;
        }
    }
    __syncthreads();

    const int arow = w * 16 + (lane & 15);
    const int koff = (lane >> 4) * 8;
    short8 a[4];
#pragma unroll
    for (int kt = 0; kt < 4; ++kt)
        a[kt] = *(const short8*)&XL[arow * 136 + kt * 32 + koff];

    floatx4 acc[8];
#pragma unroll
    for (int nt = 0; nt < 8; ++nt) acc[nt] = (floatx4){0.f, 0.f, 0.f, 0.f};

#pragma unroll
    for (int kt = 0; kt < 4; ++kt) {
#pragma unroll
        for (int nt = 0; nt < 8; ++nt) {
            short8 b = *(const short8*)&WB[((nt * 4 + kt) * 64 + lane) * 8];
            acc[nt] = __builtin_amdgcn_mfma_f32_16x16x32_bf16(a[kt], b, acc[nt], 0, 0, 0);
        }
    }
    __syncthreads();

    {
        int q = lane >> 4, cn = lane & 15;
#pragma unroll
        for (int nt = 0; nt < 8; ++nt)
#pragma unroll
            for (int r = 0; r < 4; ++r)
                Cst[(w * 16 + q * 4 + r) * 132 + nt * 16 + cn] = acc[nt][r];
    }
    __syncthreads();
    {
#pragma unroll
        for (int i = 0; i < 8; ++i) {
            int f = tid + i * 256;
            int row = f >> 5;
            int c4 = f & 31;
            int gr = blk * 64 + row;
            if (gr < N) {
                float4 v = *(float4*)&Cst[row * 132 + c4 * 4];
                float di = rsqrtf((float)(ncnt[gr] + 1));
                uint2 o;
                o.x = pack2(v.x * di, v.y * di);
                o.y = pack2(v.z * di, v.w * di);
                H[(size_t)gr * 32 + c4] = o;
            }
        }
    }
}

// --- layer-2 MFMA GEMM (bf16 input, prepacked W, dinv from ncnt) ---
__global__ __launch_bounds__(256) void gemm2_kernel(const unsigned short* __restrict__ Xv,
                                                    const short* __restrict__ wbpre,
                                                    const int* __restrict__ ncnt,
                                                    uint2* __restrict__ H, int N) {
    __shared__ __align__(16) char smem[50176];
    short* WB = (short*)smem;
    short* XL = (short*)(smem + 32768);
    float* Cst = (float*)smem;

    const int tid = threadIdx.x;
    const int w = tid >> 6;
    const int lane = tid & 63;
    const int blk = blockIdx.x;

    {
        const uint4* Wp = (const uint4*)wbpre;
        uint4* WB4 = (uint4*)WB;
#pragma unroll
        for (int i = 0; i < 8; ++i) {
            int idx = tid + i * 256;
            WB4[idx] = Wp[idx];
        }
    }
    {
#pragma unroll
        for (int i = 0; i < 8; ++i) {
            int f = tid + i * 256;
            int row = f >> 5;
            int c4 = f & 31;
            int gr = min(blk * 64 + row, N - 1);
            uint2 u = ((const uint2*)Xv)[(size_t)gr * 32 + c4];
            *(uint2*)&XL[row * 136 + c4 * 4] = u;
        }
    }
    __syncthreads();

    const int arow = w * 16 + (lane & 15);
    const int koff = (lane >> 4) * 8;
    short8 a[4];
#pragma unroll
    for (int kt = 0; kt < 4; ++kt)
        a[kt] = *(const short8*)&XL[arow * 136 + kt * 32 + koff];

    floatx4 acc[8];
#pragma unroll
    for (int nt = 0; nt < 8; ++nt) acc[nt] = (floatx4){0.f, 0.f, 0.f, 0.f};

#pragma unroll
    for (int kt = 0; kt < 4; ++kt) {
#pragma unroll
        for (int nt = 0; nt < 8; ++nt) {
            short8 b = *(const short8*)&WB[((nt * 4 + kt) * 64 + lane) * 8];
            acc[nt] = __builtin_amdgcn_mfma_f32_16x16x32_bf16(a[kt], b, acc[nt], 0, 0, 0);
        }
    }
    __syncthreads();

    {
        int q = lane >> 4, cn = lane & 15;
#pragma unroll
        for (int nt = 0; nt < 8; ++nt)
#pragma unroll
            for (int r = 0; r < 4; ++r)
                Cst[(w * 16 + q * 4 + r) * 132 + nt * 16 + cn] = acc[nt][r];
    }
    __syncthreads();
    {
#pragma unroll
        for (int i = 0; i < 8; ++i) {
            int f = tid + i * 256;
            int row = f >> 5;
            int c4 = f & 31;
            int gr = blk * 64 + row;
            if (gr < N) {
                float4 v = *(float4*)&Cst[row * 132 + c4 * 4];
                float di = rsqrtf((float)(ncnt[gr] + 1));
                uint2 o;
                o.x = pack2(v.x * di, v.y * di);
                o.y = pack2(v.z * di, v.w * di);
                H[(size_t)gr * 32 + c4] = o;
            }
        }
    }
}

// Quarter-wave (16 lanes) per node; lane holds 8 cols as uint4. fp32 accumulate.
// Node-direct CSR: start = n<<6, deg = min(ncnt[n], NCAP), dinv = rsqrt(ncnt[n]+1).
__global__ __launch_bounds__(256) void agg_kernel(const unsigned short* __restrict__ Hp,
                                                  const int* __restrict__ ncnt,
                                                  const int* __restrict__ srcs,
                                                  const float* __restrict__ bias,
                                                  unsigned short* __restrict__ Z,
                                                  int N, int do_relu) {
    int gw = (int)((blockIdx.x * blockDim.x + threadIdx.x) >> 6);
    int lane = threadIdx.x & 63;
    int q = lane >> 4;
    int hl = lane & 15;
    int n = gw * 4 + q;
    if (n >= N) return;

    const uint4* H4 = (const uint4*)Hp;
    uint4 us = H4[(size_t)n * 16 + hl];
    float4 a0 = cvt4(us.x, us.y);
    float4 a1 = cvt4(us.z, us.w);
    float4 b0 = make_float4(0.f, 0.f, 0.f, 0.f);
    float4 b1 = make_float4(0.f, 0.f, 0.f, 0.f);

    int degc = ncnt[n];
    int deg = min(degc, NCAP);
    int j = n << 6, end = j + deg;
    for (; j + 7 < end; j += 8) {
        uint4 u0 = H4[(size_t)srcs[j + 0] * 16 + hl];
        uint4 u1 = H4[(size_t)srcs[j + 1] * 16 + hl];
        uint4 u2 = H4[(size_t)srcs[j + 2] * 16 + hl];
        uint4 u3 = H4[(size_t)srcs[j + 3] * 16 + hl];
        uint4 u4 = H4[(size_t)srcs[j + 4] * 16 + hl];
        uint4 u5 = H4[(size_t)srcs[j + 5] * 16 + hl];
        uint4 u6 = H4[(size_t)srcs[j + 6] * 16 + hl];
        uint4 u7 = H4[(size_t)srcs[j + 7] * 16 + hl];
        float4 t;
        t = cvt4(u0.x, u0.y); a0.x += t.x; a0.y += t.y; a0.z += t.z; a0.w += t.w;
        t = cvt4(u0.z, u0.w); a1.x += t.x; a1.y += t.y; a1.z += t.z; a1.w += t.w;
        t = cvt4(u1.x, u1.y); b0.x += t.x; b0.y += t.y; b0.z += t.z; b0.w += t.w;
        t = cvt4(u1.z, u1.w); b1.x += t.x; b1.y += t.y; b1.z += t.z; b1.w += t.w;
        t = cvt4(u2.x, u2.y); a0.x += t.x; a0.y += t.y; a0.z += t.z; a0.w += t.w;
        t = cvt4(u2.z, u2.w); a1.x += t.x; a1.y += t.y; a1.z += t.z; a1.w += t.w;
        t = cvt4(u3.x, u3.y); b0.x += t.x; b0.y += t.y; b0.z += t.z; b0.w += t.w;
        t = cvt4(u3.z, u3.w); b1.x += t.x; b1.y += t.y; b1.z += t.z; b1.w += t.w;
        t = cvt4(u4.x, u4.y); a0.x += t.x; a0.y += t.y; a0.z += t.z; a0.w += t.w;
        t = cvt4(u4.z, u4.w); a1.x += t.x; a1.y += t.y; a1.z += t.z; a1.w += t.w;
        t = cvt4(u5.x, u5.y); b0.x += t.x; b0.y += t.y; b0.z += t.z; b0.w += t.w;
        t = cvt4(u5.z, u5.w); b1.x += t.x; b1.y += t.y; b1.z += t.z; b1.w += t.w;
        t = cvt4(u6.x, u6.y); a0.x += t.x; a0.y += t.y; a0.z += t.z; a0.w += t.w;
        t = cvt4(u6.z, u6.w); a1.x += t.x; a1.y += t.y; a1.z += t.z; a1.w += t.w;
        t = cvt4(u7.x, u7.y); b0.x += t.x; b0.y += t.y; b0.z += t.z; b0.w += t.w;
        t = cvt4(u7.z, u7.w); b1.x += t.x; b1.y += t.y; b1.z += t.z; b1.w += t.w;
    }
    for (; j + 3 < end; j += 4) {
        uint4 u0 = H4[(size_t)srcs[j + 0] * 16 + hl];
        uint4 u1 = H4[(size_t)srcs[j + 1] * 16 + hl];
        uint4 u2 = H4[(size_t)srcs[j + 2] * 16 + hl];
        uint4 u3 = H4[(size_t)srcs[j + 3] * 16 + hl];
        float4 t;
        t = cvt4(u0.x, u0.y); a0.x += t.x; a0.y += t.y; a0.z += t.z; a0.w += t.w;
        t = cvt4(u0.z, u0.w); a1.x += t.x; a1.y += t.y; a1.z += t.z; a1.w += t.w;
        t = cvt4(u1.x, u1.y); b0.x += t.x; b0.y += t.y; b0.z += t.z; b0.w += t.w;
        t = cvt4(u1.z, u1.w); b1.x += t.x; b1.y += t.y; b1.z += t.z; b1.w += t.w;
        t = cvt4(u2.x, u2.y); a0.x += t.x; a0.y += t.y; a0.z += t.z; a0.w += t.w;
        t = cvt4(u2.z, u2.w); a1.x += t.x; a1.y += t.y; a1.z += t.z; a1.w += t.w;
        t = cvt4(u3.x, u3.y); b0.x += t.x; b0.y += t.y; b0.z += t.z; b0.w += t.w;
        t = cvt4(u3.z, u3.w); b1.x += t.x; b1.y += t.y; b1.z += t.z; b1.w += t.w;
    }
    for (; j < end; ++j) {
        uint4 u = H4[(size_t)srcs[j] * 16 + hl];
        float4 t;
        t = cvt4(u.x, u.y); a0.x += t.x; a0.y += t.y; a0.z += t.z; a0.w += t.w;
        t = cvt4(u.z, u.w); a1.x += t.x; a1.y += t.y; a1.z += t.z; a1.w += t.w;
    }
    a0.x += b0.x; a0.y += b0.y; a0.z += b0.z; a0.w += b0.w;
    a1.x += b1.x; a1.y += b1.y; a1.z += b1.z; a1.w += b1.w;

    float di = rsqrtf((float)(degc + 1));
    float4 bv0 = ((const float4*)bias)[2 * hl];
    float4 bv1 = ((const float4*)bias)[2 * hl + 1];
    float o0 = di * a0.x + bv0.x, o1 = di * a0.y + bv0.y;
    float o2 = di * a0.z + bv0.z, o3 = di * a0.w + bv0.w;
    float o4 = di * a1.x + bv1.x, o5 = di * a1.y + bv1.y;
    float o6 = di * a1.z + bv1.z, o7 = di * a1.w + bv1.w;
    if (do_relu) {
        o0 = fmaxf(o0, 0.f); o1 = fmaxf(o1, 0.f); o2 = fmaxf(o2, 0.f); o3 = fmaxf(o3, 0.f);
        o4 = fmaxf(o4, 0.f); o5 = fmaxf(o5, 0.f); o6 = fmaxf(o6, 0.f); o7 = fmaxf(o7, 0.f);
    }
    uint4 o;
    o.x = pack2(o0, o1);
    o.y = pack2(o2, o3);
    o.z = pack2(o4, o5);
    o.w = pack2(o6, o7);
    ((uint4*)Z)[(size_t)n * 16 + hl] = o;
}

// Decode: pairs bucket-sorted by A, B index embedded in the record (no random pb read).
// 2 blocks per bucket; block stages the bucket's 64 A-rows (16KB) in LDS; 16-lane groups
// process 4 pairs in flight: A from LDS + B random row-gather. out[pidx] random 4B write.
__global__ __launch_bounds__(256) void decode_bucket_kernel(const unsigned short* __restrict__ Zp,
                                                            const uint2* __restrict__ stageP,
                                                            const int* __restrict__ pcnt,
                                                            float* __restrict__ out,
                                                            int N) {
    __shared__ __align__(16) short AL[64 * 136];
    const int tid = threadIdx.x;
    const int blk = blockIdx.x >> 1;
    const int half = blockIdx.x & 1;
    const uint2* SP = stageP + ((size_t)blk << 10);   // blk*PCAP
    const uint4* Z4 = (const uint4*)Zp;

    // stage A rows (coalesced; rows beyond N clamp to N-1, never referenced by pairs)
#pragma unroll
    for (int i = 0; i < 4; ++i) {
        int idx = tid + i * 256;        // [0,1024)
        int row = idx >> 4, hl = idx & 15;
        int gr = min(blk * 64 + row, N - 1);
        *(uint4*)&AL[row * 136 + hl * 8] = Z4[(size_t)gr * 16 + hl];
    }
    __syncthreads();

    int cntP = min(pcnt[blk], PCAP);
    int gp = half * 16 + (tid >> 4);    // group id in [0,32)
    int hl = tid & 15;

    for (int k = gp; k < cntP; k += 128) {
        int i1 = k + 32, i2 = k + 64, i3 = k + 96;
        bool h1 = i1 < cntP, h2 = i2 < cntP, h3 = i3 < cntP;
        uint2 r0 = SP[k];
        uint2 r1 = h1 ? SP[i1] : r0;
        uint2 r2 = h2 ? SP[i2] : r0;
        uint2 r3 = h3 ? SP[i3] : r0;
        int B0 = (int)(r0.x >> 6), B1 = (int)(r1.x >> 6);
        int B2 = (int)(r2.x >> 6), B3 = (int)(r3.x >> 6);
        uint4 ub0 = Z4[(size_t)B0 * 16 + hl];
        uint4 ub1 = Z4[(size_t)B1 * 16 + hl];
        uint4 ub2 = Z4[(size_t)B2 * 16 + hl];
        uint4 ub3 = Z4[(size_t)B3 * 16 + hl];
        uint4 ua0 = *(const uint4*)&AL[(int)(r0.x & 63u) * 136 + hl * 8];
        uint4 ua1 = *(const uint4*)&AL[(int)(r1.x & 63u) * 136 + hl * 8];
        uint4 ua2 = *(const uint4*)&AL[(int)(r2.x & 63u) * 136 + hl * 8];
        uint4 ua3 = *(const uint4*)&AL[(int)(r3.x & 63u) * 136 + hl * 8];

        float4 xa, xb, ya, yb;
        xa = cvt4(ua0.x, ua0.y); xb = cvt4(ub0.x, ub0.y);
        ya = cvt4(ua0.z, ua0.w); yb = cvt4(ub0.z, ub0.w);
        float v0 = xa.x * xb.x + xa.y * xb.y + xa.z * xb.z + xa.w * xb.w
                 + ya.x * yb.x + ya.y * yb.y + ya.z * yb.z + ya.w * yb.w;
        xa = cvt4(ua1.x, ua1.y); xb = cvt4(ub1.x, ub1.y);
        ya = cvt4(ua1.z, ua1.w); yb = cvt4(ub1.z, ub1.w);
        float v1 = xa.x * xb.x + xa.y * xb.y + xa.z * xb.z + xa.w * xb.w
                 + ya.x * yb.x + ya.y * yb.y + ya.z * yb.z + ya.w * yb.w;
        xa = cvt4(ua2.x, ua2.y); xb = cvt4(ub2.x, ub2.y);
        ya = cvt4(ua2.z, ua2.w); yb = cvt4(ub2.z, ub2.w);
        float v2 = xa.x * xb.x + xa.y * xb.y + xa.z * xb.z + xa.w * xb.w
                 + ya.x * yb.x + ya.y * yb.y + ya.z * yb.z + ya.w * yb.w;
        xa = cvt4(ua3.x, ua3.y); xb = cvt4(ub3.x, ub3.y);
        ya = cvt4(ua3.z, ua3.w); yb = cvt4(ub3.z, ub3.w);
        float v3 = xa.x * xb.x + xa.y * xb.y + xa.z * xb.z + xa.w * xb.w
                 + ya.x * yb.x + ya.y * yb.y + ya.z * yb.z + ya.w * yb.w;
#pragma unroll
        for (int off = 8; off > 0; off >>= 1) {
            v0 += __shfl_down(v0, off, 16);
            v1 += __shfl_down(v1, off, 16);
            v2 += __shfl_down(v2, off, 16);
            v3 += __shfl_down(v3, off, 16);
        }
        if (hl == 0) {
            out[r0.y] = v0;
            if (h1) out[r1.y] = v1;
            if (h2) out[r2.y] = v2;
            if (h3) out[r3.y] = v3;
        }
    }
}

extern "C" void kernel_launch(void* const* d_in, const int* in_sizes, int n_in,
                              void* d_out, int out_size, void* d_ws, size_t ws_size,
                              hipStream_t stream) {
    const int*   edge_index = (const int*)d_in[0];
    const int*   edge_pairs = (const int*)d_in[1];
    const float* emb        = (const float*)d_in[2];
    const float* W1         = (const float*)d_in[3];
    const float* b1         = (const float*)d_in[4];
    const float* W2         = (const float*)d_in[5];
    const float* b2         = (const float*)d_in[6];
    float* out = (float*)d_out;

    int E = in_sizes[0] / 2;
    int P = in_sizes[1] / 2;
    int N = in_sizes[2] / 128;
    int NB = (N + 63) / 64;    // buckets == gemm tiles (782 for N=50000; must be <= 1024)

    const int* src = edge_index;
    const int* dst = edge_index + E;
    const int* pa  = edge_pairs;
    const int* pb  = edge_pairs + P;

    char* ws = (char*)d_ws;
    size_t off = 0;
    auto alloc = [&](size_t bytes) -> void* {
        void* p = ws + off;
        off = (off + bytes + 255) & ~(size_t)255;
        return p;
    };
    unsigned short* bufA = (unsigned short*)alloc((size_t)N * 128 * 2); // h1' then h2'
    unsigned short* bufB = (unsigned short*)alloc((size_t)N * 128 * 2); // z1 then z2
    int*   srcs         = (int*)alloc((size_t)N * NCAP * sizeof(int)); // node-direct strided
    uint2* stageP       = (uint2*)alloc((size_t)NB * PCAP * sizeof(uint2));
    int*   cnts         = (int*)alloc((size_t)(N + NB) * sizeof(int)); // ncnt | pcnt
    short* wb1          = (short*)alloc((size_t)16384 * sizeof(short));
    short* wb2          = (short*)alloc((size_t)16384 * sizeof(short));
    int* ncnt = cnts;
    int* pcnt = cnts + N;

    // zero counters (~200KB)
    hipMemsetAsync(cnts, 0, (size_t)(N + NB) * sizeof(int), stream);

    // one-pass staging (node-direct edges + bucketed pairs) + W prepack
    stage1_kernel<<<STAGE_G, STAGE_T, 0, stream>>>(src, dst, pa, pb, ncnt, pcnt,
                                                   srcs, stageP, W1, W2, wb1, wb2, E, P);

    // gemm1: h1' = dinv*(emb@W1) -> bufA
    gemm1_kernel<<<NB, 256, 0, stream>>>(emb, wb1, ncnt, (uint2*)bufA, N);

    // agg1: z1 = relu(dinv*(h1'+sum)+b1) -> bufB
    agg_kernel<<<(N + 15) / 16, 256, 0, stream>>>(bufA, ncnt, srcs, b1, bufB, N, 1);

    // gemm2: h2' = dinv*(z1@W2) -> bufA
    gemm2_kernel<<<NB, 256, 0, stream>>>(bufB, wb2, ncnt, (uint2*)bufA, N);

    // agg2: z2 = dinv*(h2'+sum)+b2 -> bufB
    agg_kernel<<<(N + 15) / 16, 256, 0, stream>>>(bufA, ncnt, srcs, b2, bufB, N, 0);

    // Decode: bucket-sorted pairs, A-rows from LDS, B-rows gathered (2 blocks/bucket)
    decode_bucket_kernel<<<NB * 2, 256, 0, stream>>>(bufB, stageP, pcnt, out, N);
}

// Round 6
// 222.226 us; speedup vs baseline: 1.4423x; 1.4423x over previous
//
#include <hip/hip_runtime.h>

// GCN link predictor. fp32 math, bf16 intermediates + bf16 MFMA GEMM.
// Pipeline: memset(cnts) -> stage1[hist+reserve+scatter edges&pairs + Wprepack] ->
//           FUSED[scatter+gemm1] -> agg1 -> gemm2 -> agg2 -> decode-bucket.  (7 dispatches)
// norm factorization: h'[i] = dinv[i]*(x@W)[i];  z[i] = dinv[i]*(h'[i] + sum_{src->i} h'[src]) + b.
// R5: MFMA GEMM. R6 FAILED: hot per-row global atomics. R7: deterministic bucket CSR. R8: 248us.
// R9 FAILED: grid.sync. R10: quarter-wave gathers (neutral; random-line floor ~4.5TB/s).
// R11 FAILED: agg1+gemm2 fusion. R12: fuse scatter+gemm1 (244.8us). R13 FAILED: column-pass
// L2 blocking (no XCD locality). R14 (~neutral): decode A-bucket (4B random touches refund).
// R15 (228.7us): reserve-based staging, pb embedded in pair rec. R16 (211.4us): stage1
// occupancy 4%->full (256x1024). R17 FAILED (320us): node-direct scatter -- 4B random STORES
// write-allocate full lines (WRITE_SIZE 12->68MB); the LDS-cursor bucket scheme is load-
// bearing (converts random stores into coalesced per-(block,bucket) runs). Reverted.
// R18: R16 + counter padding: ecnt/pcnt one per 64B line (stride-16 ints). 400K reserve
// atomics-with-return previously hit 49 lines (~8K/line serialization); now 1564 lines.

typedef __attribute__((ext_vector_type(8))) short short8;   // 8 bf16 (A/B frag)
typedef __attribute__((ext_vector_type(4))) float floatx4;  // C/D frag

#define STAGE_G 256   // staging blocks
#define STAGE_T 1024  // staging threads/block
#define ECAP 2048     // per-bucket edge capacity   (lambda~1024; overflow ~impossible, guarded)
#define PCAP 1024     // per-bucket pair capacity   (lambda~511)

__device__ __forceinline__ unsigned short f2bf(float f) {
    union { float f; unsigned int u; } v; v.f = f;
    unsigned int u = v.u;
    u += 0x7fffu + ((u >> 16) & 1u);   // round-to-nearest-even
    return (unsigned short)(u >> 16);
}

__device__ __forceinline__ unsigned int pack2(float a, float b) {
    return (unsigned int)f2bf(a) | ((unsigned int)f2bf(b) << 16);
}

__device__ __forceinline__ float4 cvt4(unsigned int lo, unsigned int hi) {
    float4 f;
    f.x = __uint_as_float(lo << 16);
    f.y = __uint_as_float(lo & 0xffff0000u);
    f.z = __uint_as_float(hi << 16);
    f.w = __uint_as_float(hi & 0xffff0000u);
    return f;
}

// --- single-pass bucket staging (edges + pairs) + W prepack ---
// Per block: LDS histogram of its chunk -> one global atomicAdd range-reserve per touched
// bucket (padded counters: 1/64B line) -> LDS-cursor scatter into fixed-stride bucket
// regions (contiguous per (block,bucket) => L2 write-combined).
__global__ __launch_bounds__(1024) void stage1_kernel(const int* __restrict__ src,
                                                      const int* __restrict__ dst,
                                                      const int* __restrict__ pa,
                                                      const int* __restrict__ pb,
                                                      int* __restrict__ ecnt,
                                                      int* __restrict__ pcnt,
                                                      unsigned int* __restrict__ stageE,
                                                      uint2* __restrict__ stageP,
                                                      const float* __restrict__ W1,
                                                      const float* __restrict__ W2,
                                                      short* __restrict__ wb1,
                                                      short* __restrict__ wb2,
                                                      int E, int P, int NB) {
    __shared__ int bh[1024];
    __shared__ int bh2[1024];
    int t = threadIdx.x, g = blockIdx.x;

    // one-time W prepack into MFMA B layout: WB[((nt*4+kt)*64+ln)*8+j]  (blocks 0..7)
    if (g < 8) {
        const float4* W4 = (const float4*)((g < 4) ? W1 : W2);
        short* wb = (g < 4) ? wb1 : wb2;
        int f = ((g & 3) * 1024) + t;          // f in [0,4096)
        int k = f >> 5;
        int c4 = f & 31;
        float4 wv = W4[f];
        int kt = k >> 5, q = (k >> 3) & 3, j = k & 7;
        float e[4] = {wv.x, wv.y, wv.z, wv.w};
#pragma unroll
        for (int m = 0; m < 4; ++m) {
            int c = c4 * 4 + m;
            int nt = c >> 4;
            int ln = q * 16 + (c & 15);
            wb[((nt * 4 + kt) * 64 + ln) * 8 + j] = (short)f2bf(e[m]);
        }
    }

    for (int b = t; b < NB; b += STAGE_T) { bh[b] = 0; bh2[b] = 0; }
    __syncthreads();

    int chunk = (E + gridDim.x - 1) / gridDim.x;
    int lo = g * chunk, hi = min(lo + chunk, E);
    int chunkP = (P + gridDim.x - 1) / gridDim.x;
    int loP = g * chunkP, hiP = min(loP + chunkP, P);

    // pass 1: count
    for (int i = lo + t; i < hi; i += STAGE_T) atomicAdd(&bh[dst[i] >> 6], 1);
    for (int i = loP + t; i < hiP; i += STAGE_T) atomicAdd(&bh2[pa[i] >> 6], 1);
    __syncthreads();

    // reserve: bh[b] becomes this block's base (local index within bucket b)
    for (int b = t; b < NB; b += STAGE_T) {
        int c = bh[b];
        if (c) bh[b] = atomicAdd(&ecnt[b << 4], c);
        int c2 = bh2[b];
        if (c2) bh2[b] = atomicAdd(&pcnt[b << 4], c2);
    }
    __syncthreads();

    // pass 2: scatter into strided bucket regions
    for (int i = lo + t; i < hi; i += STAGE_T) {
        int d = dst[i];
        int b = d >> 6;
        int pos = atomicAdd(&bh[b], 1);
        if (pos < ECAP)
            stageE[(b << 11) + pos] = ((unsigned int)src[i] << 6) | (unsigned int)(d & 63);
    }
    for (int i = loP + t; i < hiP; i += STAGE_T) {
        int A = pa[i];
        int b = A >> 6;
        int pos = atomicAdd(&bh2[b], 1);
        if (pos < PCAP) {
            uint2 r;
            r.x = ((unsigned int)pb[i] << 6) | (unsigned int)(A & 63);  // B < 2^26
            r.y = (unsigned int)i;
            stageP[(b << 10) + pos] = r;
        }
    }
}

// --- FUSED scatter + layer-1 GEMM. One block per bucket b == one 64-row gemm tile.
__global__ __launch_bounds__(256) void scatter_gemm_kernel(const unsigned int* __restrict__ stageE,
                                                           const int* __restrict__ ecnt,
                                                           unsigned int* __restrict__ rpd,
                                                           float* __restrict__ dinv,
                                                           int* __restrict__ srcs_sorted,
                                                           const float* __restrict__ Xv,
                                                           const short* __restrict__ wbpre,
                                                           uint2* __restrict__ H, int N) {
    __shared__ __align__(16) char smem[50176];
    __shared__ int cnt[64];
    __shared__ int lcur[64];
    __shared__ float sdinv[64];
    short* WB = (short*)smem;            // [nt][kt][lane][j]
    short* XL = (short*)(smem + 32768);  // [row][k], row stride 136 shorts
    float* Cst = (float*)smem;           // epilogue overlay: [row][col], stride 132 floats

    const int tid = threadIdx.x;
    const int blk = blockIdx.x;

    // ---- Phase 1: bucket CSR finalize ----
    {
        int t = tid;
        int lo = blk << 6;
        int base = blk << 11;            // blk*ECAP
        int cntE = min(ecnt[blk << 4], ECAP);
        if (t < 64) cnt[t] = 0;
        __syncthreads();
        for (int i = t; i < cntE; i += 256) atomicAdd(&cnt[stageE[base + i] & 63u], 1);
        __syncthreads();
        if (t < 64) {
            int v = cnt[t];
            int inc = v;
#pragma unroll
            for (int off = 1; off < 64; off <<= 1) {
                int x = __shfl_up(inc, off, 64);
                if (t >= off) inc += x;
            }
            int exc = inc - v;
            int node = lo + t;
            int start = base + exc;      // index into strided srcs_sorted
            float di = rsqrtf((float)(v + 1));   // +1 self-loop
            if (node < N) {
                rpd[node] = ((unsigned int)start << 7) | (unsigned int)v;  // deg < 128
                dinv[node] = di;
                sdinv[t] = di;
            } else {
                sdinv[t] = 0.f;
            }
            lcur[t] = start;
        }
        __syncthreads();
        for (int i = t; i < cntE; i += 256) {
            unsigned int rec = stageE[base + i];
            int pos = atomicAdd(&lcur[rec & 63u], 1);
            srcs_sorted[pos] = (int)(rec >> 6);
        }
    }
    __syncthreads();

    // ---- Phase 2: gemm1 (fp32 X @ W -> bf16 H, dinv from LDS) ----
    {
        const uint4* Wp = (const uint4*)wbpre;
        uint4* WB4 = (uint4*)WB;
#pragma unroll
        for (int i = 0; i < 8; ++i) {
            int idx = tid + i * 256;   // [0,2048)
            WB4[idx] = Wp[idx];
        }
    }
    {
#pragma unroll
        for (int i = 0; i < 8; ++i) {
            int f = tid + i * 256;
            int row = f >> 5;
            int c4 = f & 31;
            int gr = min(blk * 64 + row, N - 1);
            float4 xv = ((const float4*)Xv)[(size_t)gr * 32 + c4];
            uint2 u;
            u.x = pack2(xv.x, xv.y);
            u.y = pack2(xv.z, xv.w);
            *(uint2*)&XL[row * 136 + c4 * 4] = u;
        }
    }
    __syncthreads();

    const int w = tid >> 6;
    const int lane = tid & 63;
    const int arow = w * 16 + (lane & 15);
    const int koff = (lane >> 4) * 8;
    short8 a[4];
#pragma unroll
    for (int kt = 0; kt < 4; ++kt)
        a[kt] = *(const short8*)&XL[arow * 136 + kt * 32 + koff];

    floatx4 acc[8];
#pragma unroll
    for (int nt = 0; nt < 8; ++nt) acc[nt] = (floatx4){0.f, 0.f, 0.f, 0.f};

#pragma unroll
    for (int kt = 0; kt < 4; ++kt) {
#pragma unroll
        for (int nt = 0; nt < 8; ++nt) {
            short8 b = *(const short8*)&WB[((nt * 4 + kt) * 64 + lane) * 8];
            acc[nt] = __builtin_amdgcn_mfma_f32_16x16x32_bf16(a[kt], b, acc[nt], 0, 0, 0);
        }
    }
    __syncthreads();

    {
        int q = lane >> 4, cn = lane & 15;
#pragma unroll
        for (int nt = 0; nt < 8; ++nt)
#pragma unroll
            for (int r = 0; r < 4; ++r)
                Cst[(w * 16 + q * 4 + r) * 132 + nt * 16 + cn] = acc[nt][r];
    }
    __syncthreads();
    {
#pragma unroll
        for (int i = 0; i < 8; ++i) {
            int f = tid + i * 256;
            int row = f >> 5;
            int c4 = f & 31;
            int gr = blk * 64 + row;
            if (gr < N) {
                float4 v = *(float4*)&Cst[row * 132 + c4 * 4];
                float di = sdinv[row];
                uint2 o;
                o.x = pack2(v.x * di, v.y * di);
                o.y = pack2(v.z * di, v.w * di);
                H[(size_t)gr * 32 + c4] = o;
            }
        }
    }
}

// --- standalone MFMA GEMM (layer 2, bf16 input, prepacked W) ---
__global__ __launch_bounds__(256) void gemm_mfma_kernel(const unsigned short* __restrict__ Xv,
                                                        const short* __restrict__ wbpre,
                                                        const float* __restrict__ dinv,
                                                        uint2* __restrict__ H, int N) {
    __shared__ __align__(16) char smem[50176];
    short* WB = (short*)smem;
    short* XL = (short*)(smem + 32768);
    float* Cst = (float*)smem;

    const int tid = threadIdx.x;
    const int w = tid >> 6;
    const int lane = tid & 63;
    const int blk = blockIdx.x;

    {
        const uint4* Wp = (const uint4*)wbpre;
        uint4* WB4 = (uint4*)WB;
#pragma unroll
        for (int i = 0; i < 8; ++i) {
            int idx = tid + i * 256;
            WB4[idx] = Wp[idx];
        }
    }
    {
#pragma unroll
        for (int i = 0; i < 8; ++i) {
            int f = tid + i * 256;
            int row = f >> 5;
            int c4 = f & 31;
            int gr = min(blk * 64 + row, N - 1);
            uint2 u = ((const uint2*)Xv)[(size_t)gr * 32 + c4];
            *(uint2*)&XL[row * 136 + c4 * 4] = u;
        }
    }
    __syncthreads();

    const int arow = w * 16 + (lane & 15);
    const int koff = (lane >> 4) * 8;
    short8 a[4];
#pragma unroll
    for (int kt = 0; kt < 4; ++kt)
        a[kt] = *(const short8*)&XL[arow * 136 + kt * 32 + koff];

    floatx4 acc[8];
#pragma unroll
    for (int nt = 0; nt < 8; ++nt) acc[nt] = (floatx4){0.f, 0.f, 0.f, 0.f};

#pragma unroll
    for (int kt = 0; kt < 4; ++kt) {
#pragma unroll
        for (int nt = 0; nt < 8; ++nt) {
            short8 b = *(const short8*)&WB[((nt * 4 + kt) * 64 + lane) * 8];
            acc[nt] = __builtin_amdgcn_mfma_f32_16x16x32_bf16(a[kt], b, acc[nt], 0, 0, 0);
        }
    }
    __syncthreads();

    {
        int q = lane >> 4, cn = lane & 15;
#pragma unroll
        for (int nt = 0; nt < 8; ++nt)
#pragma unroll
            for (int r = 0; r < 4; ++r)
                Cst[(w * 16 + q * 4 + r) * 132 + nt * 16 + cn] = acc[nt][r];
    }
    __syncthreads();
    {
#pragma unroll
        for (int i = 0; i < 8; ++i) {
            int f = tid + i * 256;
            int row = f >> 5;
            int c4 = f & 31;
            int gr = blk * 64 + row;
            if (gr < N) {
                float4 v = *(float4*)&Cst[row * 132 + c4 * 4];
                float di = dinv[gr];
                uint2 o;
                o.x = pack2(v.x * di, v.y * di);
                o.y = pack2(v.z * di, v.w * di);
                H[(size_t)gr * 32 + c4] = o;
            }
        }
    }
}

// Quarter-wave (16 lanes) per node; lane holds 8 cols as uint4. fp32 accumulate.
// rpd[n] = (start<<7)|deg into strided srcs (deg < 128, Poisson-16: safe).
__global__ __launch_bounds__(256) void agg_kernel(const unsigned short* __restrict__ Hp,
                                                  const unsigned int* __restrict__ rpd,
                                                  const int* __restrict__ srcs,
                                                  const float* __restrict__ dinv,
                                                  const float* __restrict__ bias,
                                                  unsigned short* __restrict__ Z,
                                                  int N, int do_relu) {
    int gw = (int)((blockIdx.x * blockDim.x + threadIdx.x) >> 6);
    int lane = threadIdx.x & 63;
    int q = lane >> 4;
    int hl = lane & 15;
    int n = gw * 4 + q;
    if (n >= N) return;

    const uint4* H4 = (const uint4*)Hp;
    uint4 us = H4[(size_t)n * 16 + hl];
    float4 a0 = cvt4(us.x, us.y);
    float4 a1 = cvt4(us.z, us.w);
    float4 b0 = make_float4(0.f, 0.f, 0.f, 0.f);
    float4 b1 = make_float4(0.f, 0.f, 0.f, 0.f);

    unsigned int rp = rpd[n];
    int j = (int)(rp >> 7), end = j + (int)(rp & 127u);
    for (; j + 7 < end; j += 8) {
        uint4 u0 = H4[(size_t)srcs[j + 0] * 16 + hl];
        uint4 u1 = H4[(size_t)srcs[j + 1] * 16 + hl];
        uint4 u2 = H4[(size_t)srcs[j + 2] * 16 + hl];
        uint4 u3 = H4[(size_t)srcs[j + 3] * 16 + hl];
        uint4 u4 = H4[(size_t)srcs[j + 4] * 16 + hl];
        uint4 u5 = H4[(size_t)srcs[j + 5] * 16 + hl];
        uint4 u6 = H4[(size_t)srcs[j + 6] * 16 + hl];
        uint4 u7 = H4[(size_t)srcs[j + 7] * 16 + hl];
        float4 t;
        t = cvt4(u0.x, u0.y); a0.x += t.x; a0.y += t.y; a0.z += t.z; a0.w += t.w;
        t = cvt4(u0.z, u0.w); a1.x += t.x; a1.y += t.y; a1.z += t.z; a1.w += t.w;
        t = cvt4(u1.x, u1.y); b0.x += t.x; b0.y += t.y; b0.z += t.z; b0.w += t.w;
        t = cvt4(u1.z, u1.w); b1.x += t.x; b1.y += t.y; b1.z += t.z; b1.w += t.w;
        t = cvt4(u2.x, u2.y); a0.x += t.x; a0.y += t.y; a0.z += t.z; a0.w += t.w;
        t = cvt4(u2.z, u2.w); a1.x += t.x; a1.y += t.y; a1.z += t.z; a1.w += t.w;
        t = cvt4(u3.x, u3.y); b0.x += t.x; b0.y += t.y; b0.z += t.z; b0.w += t.w;
        t = cvt4(u3.z, u3.w); b1.x += t.x; b1.y += t.y; b1.z += t.z; b1.w += t.w;
        t = cvt4(u4.x, u4.y); a0.x += t.x; a0.y += t.y; a0.z += t.z; a0.w += t.w;
        t = cvt4(u4.z, u4.w); a1.x += t.x; a1.y += t.y; a1.z += t.z; a1.w += t.w;
        t = cvt4(u5.x, u5.y); b0.x += t.x; b0.y += t.y; b0.z += t.z; b0.w += t.w;
        t = cvt4(u5.z, u5.w); b1.x += t.x; b1.y += t.y; b1.z += t.z; b1.w += t.w;
        t = cvt4(u6.x, u6.y); a0.x += t.x; a0.y += t.y; a0.z += t.z; a0.w += t.w;
        t = cvt4(u6.z, u6.w); a1.x += t.x; a1.y += t.y; a1.z += t.z; a1.w += t.w;
        t = cvt4(u7.x, u7.y); b0.x += t.x; b0.y += t.y; b0.z += t.z; b0.w += t.w;
        t = cvt4(u7.z, u7.w); b1.x += t.x; b1.y += t.y; b1.z += t.z; b1.w += t.w;
    }
    for (; j + 3 < end; j += 4) {
        uint4 u0 = H4[(size_t)srcs[j + 0] * 16 + hl];
        uint4 u1 = H4[(size_t)srcs[j + 1] * 16 + hl];
        uint4 u2 = H4[(size_t)srcs[j + 2] * 16 + hl];
        uint4 u3 = H4[(size_t)srcs[j + 3] * 16 + hl];
        float4 t;
        t = cvt4(u0.x, u0.y); a0.x += t.x; a0.y += t.y; a0.z += t.z; a0.w += t.w;
        t = cvt4(u0.z, u0.w); a1.x += t.x; a1.y += t.y; a1.z += t.z; a1.w += t.w;
        t = cvt4(u1.x, u1.y); b0.x += t.x; b0.y += t.y; b0.z += t.z; b0.w += t.w;
        t = cvt4(u1.z, u1.w); b1.x += t.x; b1.y += t.y; b1.z += t.z; b1.w += t.w;
        t = cvt4(u2.x, u2.y); a0.x += t.x; a0.y += t.y; a0.z += t.z; a0.w += t.w;
        t = cvt4(u2.z, u2.w); a1.x += t.x; a1.y += t.y; a1.z += t.z; a1.w += t.w;
        t = cvt4(u3.x, u3.y); b0.x += t.x; b0.y += t.y; b0.z += t.z; b0.w += t.w;
        t = cvt4(u3.z, u3.w); b1.x += t.x; b1.y += t.y; b1.z += t.z; b1.w += t.w;
    }
    for (; j < end; ++j) {
        uint4 u = H4[(size_t)srcs[j] * 16 + hl];
        float4 t;
        t = cvt4(u.x, u.y); a0.x += t.x; a0.y += t.y; a0.z += t.z; a0.w += t.w;
        t = cvt4(u.z, u.w); a1.x += t.x; a1.y += t.y; a1.z += t.z; a1.w += t.w;
    }
    a0.x += b0.x; a0.y += b0.y; a0.z += b0.z; a0.w += b0.w;
    a1.x += b1.x; a1.y += b1.y; a1.z += b1.z; a1.w += b1.w;

    float di = dinv[n];
    float4 bv0 = ((const float4*)bias)[2 * hl];
    float4 bv1 = ((const float4*)bias)[2 * hl + 1];
    float o0 = di * a0.x + bv0.x, o1 = di * a0.y + bv0.y;
    float o2 = di * a0.z + bv0.z, o3 = di * a0.w + bv0.w;
    float o4 = di * a1.x + bv1.x, o5 = di * a1.y + bv1.y;
    float o6 = di * a1.z + bv1.z, o7 = di * a1.w + bv1.w;
    if (do_relu) {
        o0 = fmaxf(o0, 0.f); o1 = fmaxf(o1, 0.f); o2 = fmaxf(o2, 0.f); o3 = fmaxf(o3, 0.f);
        o4 = fmaxf(o4, 0.f); o5 = fmaxf(o5, 0.f); o6 = fmaxf(o6, 0.f); o7 = fmaxf(o7, 0.f);
    }
    uint4 o;
    o.x = pack2(o0, o1);
    o.y = pack2(o2, o3);
    o.z = pack2(o4, o5);
    o.w = pack2(o6, o7);
    ((uint4*)Z)[(size_t)n * 16 + hl] = o;
}

// Decode: pairs bucket-sorted by A, B index embedded in the record (no random pb read).
// 2 blocks per bucket; block stages the bucket's 64 A-rows (16KB) in LDS; 16-lane groups
// process 4 pairs in flight: A from LDS + B random row-gather. out[pidx] random 4B write.
__global__ __launch_bounds__(256) void decode_bucket_kernel(const unsigned short* __restrict__ Zp,
                                                            const uint2* __restrict__ stageP,
                                                            const int* __restrict__ pcnt,
                                                            float* __restrict__ out,
                                                            int N) {
    __shared__ __align__(16) short AL[64 * 136];
    const int tid = threadIdx.x;
    const int blk = blockIdx.x >> 1;
    const int half = blockIdx.x & 1;
    const uint2* SP = stageP + ((size_t)blk << 10);   // blk*PCAP
    const uint4* Z4 = (const uint4*)Zp;

    // stage A rows (coalesced; rows beyond N clamp to N-1, never referenced by pairs)
#pragma unroll
    for (int i = 0; i < 4; ++i) {
        int idx = tid + i * 256;        // [0,1024)
        int row = idx >> 4, hl = idx & 15;
        int gr = min(blk * 64 + row, N - 1);
        *(uint4*)&AL[row * 136 + hl * 8] = Z4[(size_t)gr * 16 + hl];
    }
    __syncthreads();

    int cntP = min(pcnt[blk << 4], PCAP);
    int gp = half * 16 + (tid >> 4);    // group id in [0,32)
    int hl = tid & 15;

    for (int k = gp; k < cntP; k += 128) {
        int i1 = k + 32, i2 = k + 64, i3 = k + 96;
        bool h1 = i1 < cntP, h2 = i2 < cntP, h3 = i3 < cntP;
        uint2 r0 = SP[k];
        uint2 r1 = h1 ? SP[i1] : r0;
        uint2 r2 = h2 ? SP[i2] : r0;
        uint2 r3 = h3 ? SP[i3] : r0;
        int B0 = (int)(r0.x >> 6), B1 = (int)(r1.x >> 6);
        int B2 = (int)(r2.x >> 6), B3 = (int)(r3.x >> 6);
        uint4 ub0 = Z4[(size_t)B0 * 16 + hl];
        uint4 ub1 = Z4[(size_t)B1 * 16 + hl];
        uint4 ub2 = Z4[(size_t)B2 * 16 + hl];
        uint4 ub3 = Z4[(size_t)B3 * 16 + hl];
        uint4 ua0 = *(const uint4*)&AL[(int)(r0.x & 63u) * 136 + hl * 8];
        uint4 ua1 = *(const uint4*)&AL[(int)(r1.x & 63u) * 136 + hl * 8];
        uint4 ua2 = *(const uint4*)&AL[(int)(r2.x & 63u) * 136 + hl * 8];
        uint4 ua3 = *(const uint4*)&AL[(int)(r3.x & 63u) * 136 + hl * 8];

        float4 xa, xb, ya, yb;
        xa = cvt4(ua0.x, ua0.y); xb = cvt4(ub0.x, ub0.y);
        ya = cvt4(ua0.z, ua0.w); yb = cvt4(ub0.z, ub0.w);
        float v0 = xa.x * xb.x + xa.y * xb.y + xa.z * xb.z + xa.w * xb.w
                 + ya.x * yb.x + ya.y * yb.y + ya.z * yb.z + ya.w * yb.w;
        xa = cvt4(ua1.x, ua1.y); xb = cvt4(ub1.x, ub1.y);
        ya = cvt4(ua1.z, ua1.w); yb = cvt4(ub1.z, ub1.w);
        float v1 = xa.x * xb.x + xa.y * xb.y + xa.z * xb.z + xa.w * xb.w
                 + ya.x * yb.x + ya.y * yb.y + ya.z * yb.z + ya.w * yb.w;
        xa = cvt4(ua2.x, ua2.y); xb = cvt4(ub2.x, ub2.y);
        ya = cvt4(ua2.z, ua2.w); yb = cvt4(ub2.z, ub2.w);
        float v2 = xa.x * xb.x + xa.y * xb.y + xa.z * xb.z + xa.w * xb.w
                 + ya.x * yb.x + ya.y * yb.y + ya.z * yb.z + ya.w * yb.w;
        xa = cvt4(ua3.x, ua3.y); xb = cvt4(ub3.x, ub3.y);
        ya = cvt4(ua3.z, ua3.w); yb = cvt4(ub3.z, ub3.w);
        float v3 = xa.x * xb.x + xa.y * xb.y + xa.z * xb.z + xa.w * xb.w
                 + ya.x * yb.x + ya.y * yb.y + ya.z * yb.z + ya.w * yb.w;
#pragma unroll
        for (int off = 8; off > 0; off >>= 1) {
            v0 += __shfl_down(v0, off, 16);
            v1 += __shfl_down(v1, off, 16);
            v2 += __shfl_down(v2, off, 16);
            v3 += __shfl_down(v3, off, 16);
        }
        if (hl == 0) {
            out[r0.y] = v0;
            if (h1) out[r1.y] = v1;
            if (h2) out[r2.y] = v2;
            if (h3) out[r3.y] = v3;
        }
    }
}

extern "C" void kernel_launch(void* const* d_in, const int* in_sizes, int n_in,
                              void* d_out, int out_size, void* d_ws, size_t ws_size,
                              hipStream_t stream) {
    const int*   edge_index = (const int*)d_in[0];
    const int*   edge_pairs = (const int*)d_in[1];
    const float* emb        = (const float*)d_in[2];
    const float* W1         = (const float*)d_in[3];
    const float* b1         = (const float*)d_in[4];
    const float* W2         = (const float*)d_in[5];
    const float* b2         = (const float*)d_in[6];
    float* out = (float*)d_out;

    int E = in_sizes[0] / 2;
    int P = in_sizes[1] / 2;
    int N = in_sizes[2] / 128;
    int NB = (N + 63) / 64;    // buckets == gemm tiles (782 for N=50000; must be <= 1024)

    const int* src = edge_index;
    const int* dst = edge_index + E;
    const int* pa  = edge_pairs;
    const int* pb  = edge_pairs + P;

    char* ws = (char*)d_ws;
    size_t off = 0;
    auto alloc = [&](size_t bytes) -> void* {
        void* p = ws + off;
        off = (off + bytes + 255) & ~(size_t)255;
        return p;
    };
    unsigned short* bufA = (unsigned short*)alloc((size_t)N * 128 * 2); // h1' then h2'
    unsigned short* bufB = (unsigned short*)alloc((size_t)N * 128 * 2); // z1 then z2
    int*   srcs_sorted  = (int*)alloc((size_t)NB * ECAP * sizeof(int));
    unsigned int* stageE = (unsigned int*)alloc((size_t)NB * ECAP * sizeof(unsigned int));
    uint2* stageP       = (uint2*)alloc((size_t)NB * PCAP * sizeof(uint2));
    unsigned int* rpd   = (unsigned int*)alloc((size_t)N * sizeof(unsigned int));
    float* dinv         = (float*)alloc((size_t)N * sizeof(float));
    int*   cnts         = (int*)alloc((size_t)2 * NB * 16 * sizeof(int)); // padded: 1 cnt / 64B
    short* wb1          = (short*)alloc((size_t)16384 * sizeof(short));
    short* wb2          = (short*)alloc((size_t)16384 * sizeof(short));
    int* ecnt = cnts;               // access as ecnt[b<<4]
    int* pcnt = cnts + NB * 16;     // access as pcnt[b<<4]

    // zero bucket counters (100KB, trivial)
    hipMemsetAsync(cnts, 0, (size_t)2 * NB * 16 * sizeof(int), stream);

    // single-pass bucket staging (edges + pairs) + W prepack; full-occupancy launch
    stage1_kernel<<<STAGE_G, STAGE_T, 0, stream>>>(src, dst, pa, pb, ecnt, pcnt,
                                                   stageE, stageP, W1, W2, wb1, wb2,
                                                   E, P, NB);

    // FUSED scatter + gemm1: bucket CSR finalize + h1' = dinv*(emb@W1) -> bufA
    scatter_gemm_kernel<<<NB, 256, 0, stream>>>(stageE, ecnt, rpd, dinv,
                                                srcs_sorted, emb, wb1, (uint2*)bufA, N);

    // agg1: z1 = relu(dinv*(h1'+sum)+b1) -> bufB
    agg_kernel<<<(N + 15) / 16, 256, 0, stream>>>(bufA, rpd, srcs_sorted, dinv, b1,
                                                  bufB, N, 1);

    // gemm2: h2' = dinv*(z1@W2) -> bufA
    gemm_mfma_kernel<<<NB, 256, 0, stream>>>(bufB, wb2, dinv, (uint2*)bufA, N);

    // agg2: z2 = dinv*(h2'+sum)+b2 -> bufB
    agg_kernel<<<(N + 15) / 16, 256, 0, stream>>>(bufA, rpd, srcs_sorted, dinv, b2,
                                                  bufB, N, 0);

    // Decode: bucket-sorted pairs, A-rows from LDS, B-rows gathered (2 blocks/bucket)
    decode_bucket_kernel<<<NB * 2, 256, 0, stream>>>(bufB, stageP, pcnt, out, N);
}

// Round 7
// 210.912 us; speedup vs baseline: 1.5197x; 1.0536x over previous
//
#include <hip/hip_runtime.h>

// GCN link predictor. fp32 math, bf16 intermediates + bf16 MFMA GEMM.
// Pipeline: memset(cnts) -> stage1[hist+reserve+scatter edges&pairs + Wprepack] ->
//           FUSED[scatter+gemm1] -> agg1 -> gemm2 -> agg2 -> decode-bucket.  (7 dispatches)
// norm factorization: h'[i] = dinv[i]*(x@W)[i];  z[i] = dinv[i]*(h'[i] + sum_{src->i} h'[src]) + b.
// R5: MFMA GEMM. R6 FAILED: hot per-row global atomics. R7: deterministic bucket CSR. R8: 248us.
// R9 FAILED: grid.sync. R10: quarter-wave gathers (neutral; random-line floor ~4.5TB/s).
// R11 FAILED: agg1+gemm2 fusion. R12: fuse scatter+gemm1 (244.8us). R13 FAILED: column-pass
// L2 blocking (no XCD locality). R14 (~neutral): decode A-bucket (4B random touches refund).
// R15 (228.7us): reserve-based staging, pb embedded in pair rec. R16 (211.4us): stage1
// occupancy 4%->full (256x1024). R17 FAILED (320us): node-direct 4B random stores write-
// allocate full lines. R18 (~neutral/-5%): counter padding bought nothing -- reverted.
// R19 == R16 exactly (best measured). Composed floor model: aggs ~95us (3.2M random lines
// x2 at ~4.5TB/s LLC service floor, structural for uniform-random graph), decode ~28,
// stage1 ~28, gemms ~35, ramps ~15 => ~200us vs 211 measured. At roofline within ~5%.

typedef __attribute__((ext_vector_type(8))) short short8;   // 8 bf16 (A/B frag)
typedef __attribute__((ext_vector_type(4))) float floatx4;  // C/D frag

#define STAGE_G 256   // staging blocks
#define STAGE_T 1024  // staging threads/block
#define ECAP 2048     // per-bucket edge capacity   (lambda~1024; overflow ~impossible, guarded)
#define PCAP 1024     // per-bucket pair capacity   (lambda~511)

__device__ __forceinline__ unsigned short f2bf(float f) {
    union { float f; unsigned int u; } v; v.f = f;
    unsigned int u = v.u;
    u += 0x7fffu + ((u >> 16) & 1u);   // round-to-nearest-even
    return (unsigned short)(u >> 16);
}

__device__ __forceinline__ unsigned int pack2(float a, float b) {
    return (unsigned int)f2bf(a) | ((unsigned int)f2bf(b) << 16);
}

__device__ __forceinline__ float4 cvt4(unsigned int lo, unsigned int hi) {
    float4 f;
    f.x = __uint_as_float(lo << 16);
    f.y = __uint_as_float(lo & 0xffff0000u);
    f.z = __uint_as_float(hi << 16);
    f.w = __uint_as_float(hi & 0xffff0000u);
    return f;
}

// --- single-pass bucket staging (edges + pairs) + W prepack ---
// Per block: LDS histogram of its chunk -> one global atomicAdd range-reserve per touched
// bucket -> LDS-cursor scatter into fixed-stride bucket regions (contiguous per
// (block,bucket) => L2 write-combined). 256x1024: all CUs busy, 16 waves/block.
__global__ __launch_bounds__(1024) void stage1_kernel(const int* __restrict__ src,
                                                      const int* __restrict__ dst,
                                                      const int* __restrict__ pa,
                                                      const int* __restrict__ pb,
                                                      int* __restrict__ ecnt,
                                                      int* __restrict__ pcnt,
                                                      unsigned int* __restrict__ stageE,
                                                      uint2* __restrict__ stageP,
                                                      const float* __restrict__ W1,
                                                      const float* __restrict__ W2,
                                                      short* __restrict__ wb1,
                                                      short* __restrict__ wb2,
                                                      int E, int P, int NB) {
    __shared__ int bh[1024];
    __shared__ int bh2[1024];
    int t = threadIdx.x, g = blockIdx.x;

    // one-time W prepack into MFMA B layout: WB[((nt*4+kt)*64+ln)*8+j]  (blocks 0..7)
    if (g < 8) {
        const float4* W4 = (const float4*)((g < 4) ? W1 : W2);
        short* wb = (g < 4) ? wb1 : wb2;
        int f = ((g & 3) * 1024) + t;          // f in [0,4096)
        int k = f >> 5;
        int c4 = f & 31;
        float4 wv = W4[f];
        int kt = k >> 5, q = (k >> 3) & 3, j = k & 7;
        float e[4] = {wv.x, wv.y, wv.z, wv.w};
#pragma unroll
        for (int m = 0; m < 4; ++m) {
            int c = c4 * 4 + m;
            int nt = c >> 4;
            int ln = q * 16 + (c & 15);
            wb[((nt * 4 + kt) * 64 + ln) * 8 + j] = (short)f2bf(e[m]);
        }
    }

    for (int b = t; b < NB; b += STAGE_T) { bh[b] = 0; bh2[b] = 0; }
    __syncthreads();

    int chunk = (E + gridDim.x - 1) / gridDim.x;
    int lo = g * chunk, hi = min(lo + chunk, E);
    int chunkP = (P + gridDim.x - 1) / gridDim.x;
    int loP = g * chunkP, hiP = min(loP + chunkP, P);

    // pass 1: count
    for (int i = lo + t; i < hi; i += STAGE_T) atomicAdd(&bh[dst[i] >> 6], 1);
    for (int i = loP + t; i < hiP; i += STAGE_T) atomicAdd(&bh2[pa[i] >> 6], 1);
    __syncthreads();

    // reserve: bh[b] becomes this block's base (local index within bucket b)
    for (int b = t; b < NB; b += STAGE_T) {
        int c = bh[b];
        if (c) bh[b] = atomicAdd(&ecnt[b], c);
        int c2 = bh2[b];
        if (c2) bh2[b] = atomicAdd(&pcnt[b], c2);
    }
    __syncthreads();

    // pass 2: scatter into strided bucket regions
    for (int i = lo + t; i < hi; i += STAGE_T) {
        int d = dst[i];
        int b = d >> 6;
        int pos = atomicAdd(&bh[b], 1);
        if (pos < ECAP)
            stageE[(b << 11) + pos] = ((unsigned int)src[i] << 6) | (unsigned int)(d & 63);
    }
    for (int i = loP + t; i < hiP; i += STAGE_T) {
        int A = pa[i];
        int b = A >> 6;
        int pos = atomicAdd(&bh2[b], 1);
        if (pos < PCAP) {
            uint2 r;
            r.x = ((unsigned int)pb[i] << 6) | (unsigned int)(A & 63);  // B < 2^26
            r.y = (unsigned int)i;
            stageP[(b << 10) + pos] = r;
        }
    }
}

// --- FUSED scatter + layer-1 GEMM. One block per bucket b == one 64-row gemm tile.
__global__ __launch_bounds__(256) void scatter_gemm_kernel(const unsigned int* __restrict__ stageE,
                                                           const int* __restrict__ ecnt,
                                                           unsigned int* __restrict__ rpd,
                                                           float* __restrict__ dinv,
                                                           int* __restrict__ srcs_sorted,
                                                           const float* __restrict__ Xv,
                                                           const short* __restrict__ wbpre,
                                                           uint2* __restrict__ H, int N) {
    __shared__ __align__(16) char smem[50176];
    __shared__ int cnt[64];
    __shared__ int lcur[64];
    __shared__ float sdinv[64];
    short* WB = (short*)smem;            // [nt][kt][lane][j]
    short* XL = (short*)(smem + 32768);  // [row][k], row stride 136 shorts
    float* Cst = (float*)smem;           // epilogue overlay: [row][col], stride 132 floats

    const int tid = threadIdx.x;
    const int blk = blockIdx.x;

    // ---- Phase 1: bucket CSR finalize ----
    {
        int t = tid;
        int lo = blk << 6;
        int base = blk << 11;            // blk*ECAP
        int cntE = min(ecnt[blk], ECAP);
        if (t < 64) cnt[t] = 0;
        __syncthreads();
        for (int i = t; i < cntE; i += 256) atomicAdd(&cnt[stageE[base + i] & 63u], 1);
        __syncthreads();
        if (t < 64) {
            int v = cnt[t];
            int inc = v;
#pragma unroll
            for (int off = 1; off < 64; off <<= 1) {
                int x = __shfl_up(inc, off, 64);
                if (t >= off) inc += x;
            }
            int exc = inc - v;
            int node = lo + t;
            int start = base + exc;      // index into strided srcs_sorted
            float di = rsqrtf((float)(v + 1));   // +1 self-loop
            if (node < N) {
                rpd[node] = ((unsigned int)start << 7) | (unsigned int)v;  // deg < 128
                dinv[node] = di;
                sdinv[t] = di;
            } else {
                sdinv[t] = 0.f;
            }
            lcur[t] = start;
        }
        __syncthreads();
        for (int i = t; i < cntE; i += 256) {
            unsigned int rec = stageE[base + i];
            int pos = atomicAdd(&lcur[rec & 63u], 1);
            srcs_sorted[pos] = (int)(rec >> 6);
        }
    }
    __syncthreads();

    // ---- Phase 2: gemm1 (fp32 X @ W -> bf16 H, dinv from LDS) ----
    {
        const uint4* Wp = (const uint4*)wbpre;
        uint4* WB4 = (uint4*)WB;
#pragma unroll
        for (int i = 0; i < 8; ++i) {
            int idx = tid + i * 256;   // [0,2048)
            WB4[idx] = Wp[idx];
        }
    }
    {
#pragma unroll
        for (int i = 0; i < 8; ++i) {
            int f = tid + i * 256;
            int row = f >> 5;
            int c4 = f & 31;
            int gr = min(blk * 64 + row, N - 1);
            float4 xv = ((const float4*)Xv)[(size_t)gr * 32 + c4];
            uint2 u;
            u.x = pack2(xv.x, xv.y);
            u.y = pack2(xv.z, xv.w);
            *(uint2*)&XL[row * 136 + c4 * 4] = u;
        }
    }
    __syncthreads();

    const int w = tid >> 6;
    const int lane = tid & 63;
    const int arow = w * 16 + (lane & 15);
    const int koff = (lane >> 4) * 8;
    short8 a[4];
#pragma unroll
    for (int kt = 0; kt < 4; ++kt)
        a[kt] = *(const short8*)&XL[arow * 136 + kt * 32 + koff];

    floatx4 acc[8];
#pragma unroll
    for (int nt = 0; nt < 8; ++nt) acc[nt] = (floatx4){0.f, 0.f, 0.f, 0.f};

#pragma unroll
    for (int kt = 0; kt < 4; ++kt) {
#pragma unroll
        for (int nt = 0; nt < 8; ++nt) {
            short8 b = *(const short8*)&WB[((nt * 4 + kt) * 64 + lane) * 8];
            acc[nt] = __builtin_amdgcn_mfma_f32_16x16x32_bf16(a[kt], b, acc[nt], 0, 0, 0);
        }
    }
    __syncthreads();

    {
        int q = lane >> 4, cn = lane & 15;
#pragma unroll
        for (int nt = 0; nt < 8; ++nt)
#pragma unroll
            for (int r = 0; r < 4; ++r)
                Cst[(w * 16 + q * 4 + r) * 132 + nt * 16 + cn] = acc[nt][r];
    }
    __syncthreads();
    {
#pragma unroll
        for (int i = 0; i < 8; ++i) {
            int f = tid + i * 256;
            int row = f >> 5;
            int c4 = f & 31;
            int gr = blk * 64 + row;
            if (gr < N) {
                float4 v = *(float4*)&Cst[row * 132 + c4 * 4];
                float di = sdinv[row];
                uint2 o;
                o.x = pack2(v.x * di, v.y * di);
                o.y = pack2(v.z * di, v.w * di);
                H[(size_t)gr * 32 + c4] = o;
            }
        }
    }
}

// --- standalone MFMA GEMM (layer 2, bf16 input, prepacked W) ---
__global__ __launch_bounds__(256) void gemm_mfma_kernel(const unsigned short* __restrict__ Xv,
                                                        const short* __restrict__ wbpre,
                                                        const float* __restrict__ dinv,
                                                        uint2* __restrict__ H, int N) {
    __shared__ __align__(16) char smem[50176];
    short* WB = (short*)smem;
    short* XL = (short*)(smem + 32768);
    float* Cst = (float*)smem;

    const int tid = threadIdx.x;
    const int w = tid >> 6;
    const int lane = tid & 63;
    const int blk = blockIdx.x;

    {
        const uint4* Wp = (const uint4*)wbpre;
        uint4* WB4 = (uint4*)WB;
#pragma unroll
        for (int i = 0; i < 8; ++i) {
            int idx = tid + i * 256;
            WB4[idx] = Wp[idx];
        }
    }
    {
#pragma unroll
        for (int i = 0; i < 8; ++i) {
            int f = tid + i * 256;
            int row = f >> 5;
            int c4 = f & 31;
            int gr = min(blk * 64 + row, N - 1);
            uint2 u = ((const uint2*)Xv)[(size_t)gr * 32 + c4];
            *(uint2*)&XL[row * 136 + c4 * 4] = u;
        }
    }
    __syncthreads();

    const int arow = w * 16 + (lane & 15);
    const int koff = (lane >> 4) * 8;
    short8 a[4];
#pragma unroll
    for (int kt = 0; kt < 4; ++kt)
        a[kt] = *(const short8*)&XL[arow * 136 + kt * 32 + koff];

    floatx4 acc[8];
#pragma unroll
    for (int nt = 0; nt < 8; ++nt) acc[nt] = (floatx4){0.f, 0.f, 0.f, 0.f};

#pragma unroll
    for (int kt = 0; kt < 4; ++kt) {
#pragma unroll
        for (int nt = 0; nt < 8; ++nt) {
            short8 b = *(const short8*)&WB[((nt * 4 + kt) * 64 + lane) * 8];
            acc[nt] = __builtin_amdgcn_mfma_f32_16x16x32_bf16(a[kt], b, acc[nt], 0, 0, 0);
        }
    }
    __syncthreads();

    {
        int q = lane >> 4, cn = lane & 15;
#pragma unroll
        for (int nt = 0; nt < 8; ++nt)
#pragma unroll
            for (int r = 0; r < 4; ++r)
                Cst[(w * 16 + q * 4 + r) * 132 + nt * 16 + cn] = acc[nt][r];
    }
    __syncthreads();
    {
#pragma unroll
        for (int i = 0; i < 8; ++i) {
            int f = tid + i * 256;
            int row = f >> 5;
            int c4 = f & 31;
            int gr = blk * 64 + row;
            if (gr < N) {
                float4 v = *(float4*)&Cst[row * 132 + c4 * 4];
                float di = dinv[gr];
                uint2 o;
                o.x = pack2(v.x * di, v.y * di);
                o.y = pack2(v.z * di, v.w * di);
                H[(size_t)gr * 32 + c4] = o;
            }
        }
    }
}

// Quarter-wave (16 lanes) per node; lane holds 8 cols as uint4. fp32 accumulate.
// rpd[n] = (start<<7)|deg into strided srcs (deg < 128, Poisson-16: safe).
__global__ __launch_bounds__(256) void agg_kernel(const unsigned short* __restrict__ Hp,
                                                  const unsigned int* __restrict__ rpd,
                                                  const int* __restrict__ srcs,
                                                  const float* __restrict__ dinv,
                                                  const float* __restrict__ bias,
                                                  unsigned short* __restrict__ Z,
                                                  int N, int do_relu) {
    int gw = (int)((blockIdx.x * blockDim.x + threadIdx.x) >> 6);
    int lane = threadIdx.x & 63;
    int q = lane >> 4;
    int hl = lane & 15;
    int n = gw * 4 + q;
    if (n >= N) return;

    const uint4* H4 = (const uint4*)Hp;
    uint4 us = H4[(size_t)n * 16 + hl];
    float4 a0 = cvt4(us.x, us.y);
    float4 a1 = cvt4(us.z, us.w);
    float4 b0 = make_float4(0.f, 0.f, 0.f, 0.f);
    float4 b1 = make_float4(0.f, 0.f, 0.f, 0.f);

    unsigned int rp = rpd[n];
    int j = (int)(rp >> 7), end = j + (int)(rp & 127u);
    for (; j + 7 < end; j += 8) {
        uint4 u0 = H4[(size_t)srcs[j + 0] * 16 + hl];
        uint4 u1 = H4[(size_t)srcs[j + 1] * 16 + hl];
        uint4 u2 = H4[(size_t)srcs[j + 2] * 16 + hl];
        uint4 u3 = H4[(size_t)srcs[j + 3] * 16 + hl];
        uint4 u4 = H4[(size_t)srcs[j + 4] * 16 + hl];
        uint4 u5 = H4[(size_t)srcs[j + 5] * 16 + hl];
        uint4 u6 = H4[(size_t)srcs[j + 6] * 16 + hl];
        uint4 u7 = H4[(size_t)srcs[j + 7] * 16 + hl];
        float4 t;
        t = cvt4(u0.x, u0.y); a0.x += t.x; a0.y += t.y; a0.z += t.z; a0.w += t.w;
        t = cvt4(u0.z, u0.w); a1.x += t.x; a1.y += t.y; a1.z += t.z; a1.w += t.w;
        t = cvt4(u1.x, u1.y); b0.x += t.x; b0.y += t.y; b0.z += t.z; b0.w += t.w;
        t = cvt4(u1.z, u1.w); b1.x += t.x; b1.y += t.y; b1.z += t.z; b1.w += t.w;
        t = cvt4(u2.x, u2.y); a0.x += t.x; a0.y += t.y; a0.z += t.z; a0.w += t.w;
        t = cvt4(u2.z, u2.w); a1.x += t.x; a1.y += t.y; a1.z += t.z; a1.w += t.w;
        t = cvt4(u3.x, u3.y); b0.x += t.x; b0.y += t.y; b0.z += t.z; b0.w += t.w;
        t = cvt4(u3.z, u3.w); b1.x += t.x; b1.y += t.y; b1.z += t.z; b1.w += t.w;
        t = cvt4(u4.x, u4.y); a0.x += t.x; a0.y += t.y; a0.z += t.z; a0.w += t.w;
        t = cvt4(u4.z, u4.w); a1.x += t.x; a1.y += t.y; a1.z += t.z; a1.w += t.w;
        t = cvt4(u5.x, u5.y); b0.x += t.x; b0.y += t.y; b0.z += t.z; b0.w += t.w;
        t = cvt4(u5.z, u5.w); b1.x += t.x; b1.y += t.y; b1.z += t.z; b1.w += t.w;
        t = cvt4(u6.x, u6.y); a0.x += t.x; a0.y += t.y; a0.z += t.z; a0.w += t.w;
        t = cvt4(u6.z, u6.w); a1.x += t.x; a1.y += t.y; a1.z += t.z; a1.w += t.w;
        t = cvt4(u7.x, u7.y); b0.x += t.x; b0.y += t.y; b0.z += t.z; b0.w += t.w;
        t = cvt4(u7.z, u7.w); b1.x += t.x; b1.y += t.y; b1.z += t.z; b1.w += t.w;
    }
    for (; j + 3 < end; j += 4) {
        uint4 u0 = H4[(size_t)srcs[j + 0] * 16 + hl];
        uint4 u1 = H4[(size_t)srcs[j + 1] * 16 + hl];
        uint4 u2 = H4[(size_t)srcs[j + 2] * 16 + hl];
        uint4 u3 = H4[(size_t)srcs[j + 3] * 16 + hl];
        float4 t;
        t = cvt4(u0.x, u0.y); a0.x += t.x; a0.y += t.y; a0.z += t.z; a0.w += t.w;
        t = cvt4(u0.z, u0.w); a1.x += t.x; a1.y += t.y; a1.z += t.z; a1.w += t.w;
        t = cvt4(u1.x, u1.y); b0.x += t.x; b0.y += t.y; b0.z += t.z; b0.w += t.w;
        t = cvt4(u1.z, u1.w); b1.x += t.x; b1.y += t.y; b1.z += t.z; b1.w += t.w;
        t = cvt4(u2.x, u2.y); a0.x += t.x; a0.y += t.y; a0.z += t.z; a0.w += t.w;
        t = cvt4(u2.z, u2.w); a1.x += t.x; a1.y += t.y; a1.z += t.z; a1.w += t.w;
        t = cvt4(u3.x, u3.y); b0.x += t.x; b0.y += t.y; b0.z += t.z; b0.w += t.w;
        t = cvt4(u3.z, u3.w); b1.x += t.x; b1.y += t.y; b1.z += t.z; b1.w += t.w;
    }
    for (; j < end; ++j) {
        uint4 u = H4[(size_t)srcs[j] * 16 + hl];
        float4 t;
        t = cvt4(u.x, u.y); a0.x += t.x; a0.y += t.y; a0.z += t.z; a0.w += t.w;
        t = cvt4(u.z, u.w); a1.x += t.x; a1.y += t.y; a1.z += t.z; a1.w += t.w;
    }
    a0.x += b0.x; a0.y += b0.y; a0.z += b0.z; a0.w += b0.w;
    a1.x += b1.x; a1.y += b1.y; a1.z += b1.z; a1.w += b1.w;

    float di = dinv[n];
    float4 bv0 = ((const float4*)bias)[2 * hl];
    float4 bv1 = ((const float4*)bias)[2 * hl + 1];
    float o0 = di * a0.x + bv0.x, o1 = di * a0.y + bv0.y;
    float o2 = di * a0.z + bv0.z, o3 = di * a0.w + bv0.w;
    float o4 = di * a1.x + bv1.x, o5 = di * a1.y + bv1.y;
    float o6 = di * a1.z + bv1.z, o7 = di * a1.w + bv1.w;
    if (do_relu) {
        o0 = fmaxf(o0, 0.f); o1 = fmaxf(o1, 0.f); o2 = fmaxf(o2, 0.f); o3 = fmaxf(o3, 0.f);
        o4 = fmaxf(o4, 0.f); o5 = fmaxf(o5, 0.f); o6 = fmaxf(o6, 0.f); o7 = fmaxf(o7, 0.f);
    }
    uint4 o;
    o.x = pack2(o0, o1);
    o.y = pack2(o2, o3);
    o.z = pack2(o4, o5);
    o.w = pack2(o6, o7);
    ((uint4*)Z)[(size_t)n * 16 + hl] = o;
}

// Decode: pairs bucket-sorted by A, B index embedded in the record (no random pb read).
// 2 blocks per bucket; block stages the bucket's 64 A-rows (16KB) in LDS; 16-lane groups
// process 4 pairs in flight: A from LDS + B random row-gather. out[pidx] random 4B write.
__global__ __launch_bounds__(256) void decode_bucket_kernel(const unsigned short* __restrict__ Zp,
                                                            const uint2* __restrict__ stageP,
                                                            const int* __restrict__ pcnt,
                                                            float* __restrict__ out,
                                                            int N) {
    __shared__ __align__(16) short AL[64 * 136];
    const int tid = threadIdx.x;
    const int blk = blockIdx.x >> 1;
    const int half = blockIdx.x & 1;
    const uint2* SP = stageP + ((size_t)blk << 10);   // blk*PCAP
    const uint4* Z4 = (const uint4*)Zp;

    // stage A rows (coalesced; rows beyond N clamp to N-1, never referenced by pairs)
#pragma unroll
    for (int i = 0; i < 4; ++i) {
        int idx = tid + i * 256;        // [0,1024)
        int row = idx >> 4, hl = idx & 15;
        int gr = min(blk * 64 + row, N - 1);
        *(uint4*)&AL[row * 136 + hl * 8] = Z4[(size_t)gr * 16 + hl];
    }
    __syncthreads();

    int cntP = min(pcnt[blk], PCAP);
    int gp = half * 16 + (tid >> 4);    // group id in [0,32)
    int hl = tid & 15;

    for (int k = gp; k < cntP; k += 128) {
        int i1 = k + 32, i2 = k + 64, i3 = k + 96;
        bool h1 = i1 < cntP, h2 = i2 < cntP, h3 = i3 < cntP;
        uint2 r0 = SP[k];
        uint2 r1 = h1 ? SP[i1] : r0;
        uint2 r2 = h2 ? SP[i2] : r0;
        uint2 r3 = h3 ? SP[i3] : r0;
        int B0 = (int)(r0.x >> 6), B1 = (int)(r1.x >> 6);
        int B2 = (int)(r2.x >> 6), B3 = (int)(r3.x >> 6);
        uint4 ub0 = Z4[(size_t)B0 * 16 + hl];
        uint4 ub1 = Z4[(size_t)B1 * 16 + hl];
        uint4 ub2 = Z4[(size_t)B2 * 16 + hl];
        uint4 ub3 = Z4[(size_t)B3 * 16 + hl];
        uint4 ua0 = *(const uint4*)&AL[(int)(r0.x & 63u) * 136 + hl * 8];
        uint4 ua1 = *(const uint4*)&AL[(int)(r1.x & 63u) * 136 + hl * 8];
        uint4 ua2 = *(const uint4*)&AL[(int)(r2.x & 63u) * 136 + hl * 8];
        uint4 ua3 = *(const uint4*)&AL[(int)(r3.x & 63u) * 136 + hl * 8];

        float4 xa, xb, ya, yb;
        xa = cvt4(ua0.x, ua0.y); xb = cvt4(ub0.x, ub0.y);
        ya = cvt4(ua0.z, ua0.w); yb = cvt4(ub0.z, ub0.w);
        float v0 = xa.x * xb.x + xa.y * xb.y + xa.z * xb.z + xa.w * xb.w
                 + ya.x * yb.x + ya.y * yb.y + ya.z * yb.z + ya.w * yb.w;
        xa = cvt4(ua1.x, ua1.y); xb = cvt4(ub1.x, ub1.y);
        ya = cvt4(ua1.z, ua1.w); yb = cvt4(ub1.z, ub1.w);
        float v1 = xa.x * xb.x + xa.y * xb.y + xa.z * xb.z + xa.w * xb.w
                 + ya.x * yb.x + ya.y * yb.y + ya.z * yb.z + ya.w * yb.w;
        xa = cvt4(ua2.x, ua2.y); xb = cvt4(ub2.x, ub2.y);
        ya = cvt4(ua2.z, ua2.w); yb = cvt4(ub2.z, ub2.w);
        float v2 = xa.x * xb.x + xa.y * xb.y + xa.z * xb.z + xa.w * xb.w
                 + ya.x * yb.x + ya.y * yb.y + ya.z * yb.z + ya.w * yb.w;
        xa = cvt4(ua3.x, ua3.y); xb = cvt4(ub3.x, ub3.y);
        ya = cvt4(ua3.z, ua3.w); yb = cvt4(ub3.z, ub3.w);
        float v3 = xa.x * xb.x + xa.y * xb.y + xa.z * xb.z + xa.w * xb.w
                 + ya.x * yb.x + ya.y * yb.y + ya.z * yb.z + ya.w * yb.w;
#pragma unroll
        for (int off = 8; off > 0; off >>= 1) {
            v0 += __shfl_down(v0, off, 16);
            v1 += __shfl_down(v1, off, 16);
            v2 += __shfl_down(v2, off, 16);
            v3 += __shfl_down(v3, off, 16);
        }
        if (hl == 0) {
            out[r0.y] = v0;
            if (h1) out[r1.y] = v1;
            if (h2) out[r2.y] = v2;
            if (h3) out[r3.y] = v3;
        }
    }
}

extern "C" void kernel_launch(void* const* d_in, const int* in_sizes, int n_in,
                              void* d_out, int out_size, void* d_ws, size_t ws_size,
                              hipStream_t stream) {
    const int*   edge_index = (const int*)d_in[0];
    const int*   edge_pairs = (const int*)d_in[1];
    const float* emb        = (const float*)d_in[2];
    const float* W1         = (const float*)d_in[3];
    const float* b1         = (const float*)d_in[4];
    const float* W2         = (const float*)d_in[5];
    const float* b2         = (const float*)d_in[6];
    float* out = (float*)d_out;

    int E = in_sizes[0] / 2;
    int P = in_sizes[1] / 2;
    int N = in_sizes[2] / 128;
    int NB = (N + 63) / 64;    // buckets == gemm tiles (782 for N=50000; must be <= 1024)

    const int* src = edge_index;
    const int* dst = edge_index + E;
    const int* pa  = edge_pairs;
    const int* pb  = edge_pairs + P;

    char* ws = (char*)d_ws;
    size_t off = 0;
    auto alloc = [&](size_t bytes) -> void* {
        void* p = ws + off;
        off = (off + bytes + 255) & ~(size_t)255;
        return p;
    };
    unsigned short* bufA = (unsigned short*)alloc((size_t)N * 128 * 2); // h1' then h2'
    unsigned short* bufB = (unsigned short*)alloc((size_t)N * 128 * 2); // z1 then z2
    int*   srcs_sorted  = (int*)alloc((size_t)NB * ECAP * sizeof(int));
    unsigned int* stageE = (unsigned int*)alloc((size_t)NB * ECAP * sizeof(unsigned int));
    uint2* stageP       = (uint2*)alloc((size_t)NB * PCAP * sizeof(uint2));
    unsigned int* rpd   = (unsigned int*)alloc((size_t)N * sizeof(unsigned int));
    float* dinv         = (float*)alloc((size_t)N * sizeof(float));
    int*   cnts         = (int*)alloc((size_t)2 * NB * sizeof(int));  // ecnt | pcnt
    short* wb1          = (short*)alloc((size_t)16384 * sizeof(short));
    short* wb2          = (short*)alloc((size_t)16384 * sizeof(short));
    int* ecnt = cnts;
    int* pcnt = cnts + NB;

    // zero bucket counters (tiny)
    hipMemsetAsync(cnts, 0, (size_t)2 * NB * sizeof(int), stream);

    // single-pass bucket staging (edges + pairs) + W prepack; full-occupancy launch
    stage1_kernel<<<STAGE_G, STAGE_T, 0, stream>>>(src, dst, pa, pb, ecnt, pcnt,
                                                   stageE, stageP, W1, W2, wb1, wb2,
                                                   E, P, NB);

    // FUSED scatter + gemm1: bucket CSR finalize + h1' = dinv*(emb@W1) -> bufA
    scatter_gemm_kernel<<<NB, 256, 0, stream>>>(stageE, ecnt, rpd, dinv,
                                                srcs_sorted, emb, wb1, (uint2*)bufA, N);

    // agg1: z1 = relu(dinv*(h1'+sum)+b1) -> bufB
    agg_kernel<<<(N + 15) / 16, 256, 0, stream>>>(bufA, rpd, srcs_sorted, dinv, b1,
                                                  bufB, N, 1);

    // gemm2: h2' = dinv*(z1@W2) -> bufA
    gemm_mfma_kernel<<<NB, 256, 0, stream>>>(bufB, wb2, dinv, (uint2*)bufA, N);

    // agg2: z2 = dinv*(h2'+sum)+b2 -> bufB
    agg_kernel<<<(N + 15) / 16, 256, 0, stream>>>(bufA, rpd, srcs_sorted, dinv, b2,
                                                  bufB, N, 0);

    // Decode: bucket-sorted pairs, A-rows from LDS, B-rows gathered (2 blocks/bucket)
    decode_bucket_kernel<<<NB * 2, 256, 0, stream>>>(bufB, stageP, pcnt, out, N);
}